// Round 3
// baseline (1373.994 us; speedup 1.0000x reference)
//
#include <hip/hip_runtime.h>

#define NBINS  16
#define TPB    256
#define BLOCKS 768         // 3 blocks/CU co-resident (LDS-bound: 3 x 48KB < 160KB)

// Fire-and-forget LDS float add: emits ds_add_f32 (no return -> no lgkmcnt
// dependency chain). Atomicity is NOT required for correctness here (each
// thread owns its column), so any fallback is still correct.
__device__ inline void lds_fadd(float* p, float v) {
#if defined(__has_builtin) && __has_builtin(__builtin_amdgcn_ds_faddf)
    (void)__builtin_amdgcn_ds_faddf(
        (__attribute__((address_space(3))) float*)p, v, 0, 0, false);
#else
    (void)unsafeAtomicAdd(p, v);   // hardware fadd path (gfx90a+)
#endif
}

// d_ws layout: partial[cell * BLOCKS + blockIdx]; cells 0..15 cnt, 16..31 sum,
// 32..47 sumsq, 48 = sum (wq-w)^2.  49*768 floats ≈ 150 KB.

__global__ __launch_bounds__(TPB) void binreg_main(
    const float* __restrict__ w, const float* __restrict__ wq,
    const float* __restrict__ alpha_p, const int* __restrict__ nbit_p,
    float* __restrict__ partial, long long n)
{
    // Column layout: plane[bin][tid]. Address = bin*256 + tid -> bank = tid%32
    // for every access regardless of bin => deterministic 2-way aliasing (free).
    __shared__ float c_pl [NBINS * TPB];
    __shared__ float s_pl [NBINS * TPB];
    __shared__ float ss_pl[NBINS * TPB];
    __shared__ float sqpart[TPB / 64];

    const int tid = threadIdx.x;

    #pragma unroll
    for (int k = 0; k < NBINS; ++k) {
        c_pl [k * TPB + tid] = 0.0f;
        s_pl [k * TPB + tid] = 0.0f;
        ss_pl[k * TPB + tid] = 0.0f;
    }
    // no barrier needed: columns are thread-private until the epilogue fold

    const float inv_a = 1.0f / alpha_p[0];
    const int   qoff  = 1 << (nbit_p[0] - 1);   // -Qn = 8 for nbit=4

    const long long n4     = n >> 2;
    const long long stride = (long long)BLOCKS * TPB;
    const float4* w4 = (const float4*)w;
    const float4* q4 = (const float4*)wq;

    float sq = 0.0f;

    for (long long i = (long long)blockIdx.x * TPB + tid; i < n4; i += stride) {
        float4 a = w4[i];
        float4 b = q4[i];

        float d0 = b.x - a.x, d1 = b.y - a.y, d2 = b.z - a.z, d3 = b.w - a.w;
        sq += d0 * d0 + d1 * d1 + d2 * d2 + d3 * d3;

        int i0 = ((((int)rintf(b.x * inv_a) + qoff) & (NBINS - 1)) << 8) + tid;
        int i1 = ((((int)rintf(b.y * inv_a) + qoff) & (NBINS - 1)) << 8) + tid;
        int i2 = ((((int)rintf(b.z * inv_a) + qoff) & (NBINS - 1)) << 8) + tid;
        int i3 = ((((int)rintf(b.w * inv_a) + qoff) & (NBINS - 1)) << 8) + tid;

        lds_fadd(&c_pl[i0], 1.0f); lds_fadd(&s_pl[i0], a.x); lds_fadd(&ss_pl[i0], a.x * a.x);
        lds_fadd(&c_pl[i1], 1.0f); lds_fadd(&s_pl[i1], a.y); lds_fadd(&ss_pl[i1], a.y * a.y);
        lds_fadd(&c_pl[i2], 1.0f); lds_fadd(&s_pl[i2], a.z); lds_fadd(&ss_pl[i2], a.z * a.z);
        lds_fadd(&c_pl[i3], 1.0f); lds_fadd(&s_pl[i3], a.w); lds_fadd(&ss_pl[i3], a.w * a.w);
    }

    // scalar tail (n divisible by 4 in practice; safety only)
    for (long long i = (n4 << 2) + (long long)blockIdx.x * TPB + tid; i < n; i += stride) {
        float a = w[i], b = wq[i];
        float d = b - a;
        sq += d * d;
        int ii = ((((int)rintf(b * inv_a) + qoff) & (NBINS - 1)) << 8) + tid;
        lds_fadd(&c_pl[ii], 1.0f); lds_fadd(&s_pl[ii], a); lds_fadd(&ss_pl[ii], a * a);
    }

    // wave-reduce sq
    for (int off = 32; off; off >>= 1) sq += __shfl_down(sq, off, 64);
    const int wave = tid >> 6, lane = tid & 63;
    if (lane == 0) sqpart[wave] = sq;
    __syncthreads();   // drains ds_add queue (lgkmcnt) + makes columns visible

    // fold 256 columns -> 48 block partials; wave v handles cells v, v+4, ...
    for (int c = wave; c < 48; c += 4) {
        const float* pl = (c < 16) ? c_pl : (c < 32) ? s_pl : ss_pl;
        const int bin = c & 15;
        float v = 0.0f;
        #pragma unroll
        for (int r = 0; r < TPB / 64; ++r)
            v += pl[(bin << 8) + r * 64 + lane];
        for (int off = 32; off; off >>= 1) v += __shfl_down(v, off, 64);
        if (lane == 0) partial[c * BLOCKS + blockIdx.x] = v;
    }
    if (tid == 0)
        partial[48 * BLOCKS + blockIdx.x] =
            sqpart[0] + sqpart[1] + sqpart[2] + sqpart[3];
}

__global__ __launch_bounds__(TPB) void binreg_final(
    const float* __restrict__ partial, float* __restrict__ out, long long n)
{
    __shared__ float cell[49];
    const int tid = threadIdx.x, wave = tid >> 6, lane = tid & 63;

    for (int c = wave; c < 49; c += 4) {
        // 4 independent accumulators -> batched loads, no dependent-load chain
        float v0 = 0.0f, v1 = 0.0f, v2 = 0.0f, v3 = 0.0f;
        for (int r = lane; r < BLOCKS; r += 256) {
            v0 += partial[c * BLOCKS + r];
            v1 += partial[c * BLOCKS + r + 64];
            v2 += partial[c * BLOCKS + r + 128];
            v3 += partial[c * BLOCKS + r + 192];
        }
        float v = (v0 + v1) + (v2 + v3);
        for (int off = 32; off; off >>= 1) v += __shfl_down(v, off, 64);
        if (lane == 0) cell[c] = v;
    }
    __syncthreads();

    if (tid == 0) {
        float loss = cell[48] / (float)n;   // mean squared diff
        #pragma unroll
        for (int b = 0; b < NBINS; ++b) {
            float cnt = cell[b];
            float s   = cell[16 + b];
            float ss  = cell[32 + b];
            if (cnt > 1.0f)
                loss += (ss - s * s / cnt) / (cnt - 1.0f);  // unbiased var
        }
        out[0] = 0.1f * loss;   // LMBDA
    }
}

extern "C" void kernel_launch(void* const* d_in, const int* in_sizes, int n_in,
                              void* d_out, int out_size, void* d_ws, size_t ws_size,
                              hipStream_t stream)
{
    const float* w     = (const float*)d_in[0];
    const float* wq    = (const float*)d_in[1];
    const int*   nbit  = (const int*)d_in[2];
    const float* alpha = (const float*)d_in[3];
    float* out     = (float*)d_out;
    float* partial = (float*)d_ws;   // fully overwritten each call; no memset needed
    long long n = (long long)in_sizes[0];

    binreg_main<<<BLOCKS, TPB, 0, stream>>>(w, wq, alpha, nbit, partial, n);
    binreg_final<<<1, TPB, 0, stream>>>(partial, out, n);
}

// Round 4
// 517.178 us; speedup vs baseline: 2.6567x; 2.6567x over previous
//
#include <hip/hip_runtime.h>

#define NBINS  16
#define TPB    256
#define BLOCKS 768         // 3 blocks/CU co-resident (48KB LDS x 3 = 144KB < 160KB)
#define PLANE  (NBINS * TPB)

// d_ws layout: partial[cell * BLOCKS + blockIdx]; cells 0..15 cnt, 16..31 sum,
// 32..47 sumsq, 48 = sum (wq-w)^2.  49*768 floats ≈ 150 KB.
//
// Histogram storage: column layout plane[bin][tid] -> LDS bank = tid % 32 for
// every access REGARDLESS of the data-dependent bin => deterministic 2-way
// aliasing (free, m136). {sum, sumsq} packed as float2 -> ds_read_b64/write_b64.
// Plain read-modify-write, NO atomics: ds_add_f32 / CAS both measured ~6x
// slower than the RMW path (R1/R3 vs R2).

__global__ __launch_bounds__(TPB) void binreg_main(
    const float* __restrict__ w, const float* __restrict__ wq,
    const float* __restrict__ alpha_p, const int* __restrict__ nbit_p,
    float* __restrict__ partial, long long n)
{
    __shared__ float  c_pl [PLANE];   // per-bin count,  16 KB
    __shared__ float2 sv_pl[PLANE];   // {sum, sumsq},   32 KB
    __shared__ float  sqpart[TPB / 64];

    const int tid = threadIdx.x;

    #pragma unroll
    for (int k = 0; k < NBINS; ++k) {
        c_pl [k * TPB + tid] = 0.0f;
        sv_pl[k * TPB + tid] = make_float2(0.0f, 0.0f);
    }
    // columns are thread-private until the epilogue fold; no barrier needed

    const float inv_a = 1.0f / alpha_p[0];
    const int   qoff  = 1 << (nbit_p[0] - 1);   // -Qn = 8 for nbit=4

    const long long n4     = n >> 2;
    const long long stride = (long long)BLOCKS * TPB;
    const float4* w4 = (const float4*)w;
    const float4* q4 = (const float4*)wq;

    float sq = 0.0f;

    for (long long i = (long long)blockIdx.x * TPB + tid; i < n4; i += stride) {
        float4 a = w4[i];
        float4 b = q4[i];

        float d0 = b.x - a.x, d1 = b.y - a.y, d2 = b.z - a.z, d3 = b.w - a.w;
        sq += d0 * d0 + d1 * d1 + d2 * d2 + d3 * d3;

        int i0 = ((((int)rintf(b.x * inv_a) + qoff) & (NBINS - 1)) << 8) + tid;
        int i1 = ((((int)rintf(b.y * inv_a) + qoff) & (NBINS - 1)) << 8) + tid;
        int i2 = ((((int)rintf(b.z * inv_a) + qoff) & (NBINS - 1)) << 8) + tid;
        int i3 = ((((int)rintf(b.w * inv_a) + qoff) & (NBINS - 1)) << 8) + tid;

        { c_pl[i0] += 1.0f; float2 t = sv_pl[i0]; t.x += a.x; t.y += a.x * a.x; sv_pl[i0] = t; }
        { c_pl[i1] += 1.0f; float2 t = sv_pl[i1]; t.x += a.y; t.y += a.y * a.y; sv_pl[i1] = t; }
        { c_pl[i2] += 1.0f; float2 t = sv_pl[i2]; t.x += a.z; t.y += a.z * a.z; sv_pl[i2] = t; }
        { c_pl[i3] += 1.0f; float2 t = sv_pl[i3]; t.x += a.w; t.y += a.w * a.w; sv_pl[i3] = t; }
    }

    // scalar tail (n divisible by 4 in practice; safety only)
    for (long long i = (n4 << 2) + (long long)blockIdx.x * TPB + tid; i < n; i += stride) {
        float a = w[i], b = wq[i];
        float d = b - a;
        sq += d * d;
        int ii = ((((int)rintf(b * inv_a) + qoff) & (NBINS - 1)) << 8) + tid;
        c_pl[ii] += 1.0f; float2 t = sv_pl[ii]; t.x += a; t.y += a * a; sv_pl[ii] = t;
    }

    // wave-reduce sq
    for (int off = 32; off; off >>= 1) sq += __shfl_down(sq, off, 64);
    const int wave = tid >> 6, lane = tid & 63;
    if (lane == 0) sqpart[wave] = sq;
    __syncthreads();

    // fold 256 columns -> 48 block partials; wave v handles cells v, v+4, ...
    for (int c = wave; c < 48; c += 4) {
        const int bin = c & 15;
        float v = 0.0f;
        if (c < 16) {
            #pragma unroll
            for (int r = 0; r < TPB / 64; ++r)
                v += c_pl[(bin << 8) + r * 64 + lane];
        } else if (c < 32) {
            #pragma unroll
            for (int r = 0; r < TPB / 64; ++r)
                v += sv_pl[(bin << 8) + r * 64 + lane].x;
        } else {
            #pragma unroll
            for (int r = 0; r < TPB / 64; ++r)
                v += sv_pl[(bin << 8) + r * 64 + lane].y;
        }
        for (int off = 32; off; off >>= 1) v += __shfl_down(v, off, 64);
        if (lane == 0) partial[c * BLOCKS + blockIdx.x] = v;
    }
    if (tid == 0)
        partial[48 * BLOCKS + blockIdx.x] =
            sqpart[0] + sqpart[1] + sqpart[2] + sqpart[3];
}

__global__ __launch_bounds__(TPB) void binreg_final(
    const float* __restrict__ partial, float* __restrict__ out, long long n)
{
    __shared__ float cell[49];
    const int tid = threadIdx.x, wave = tid >> 6, lane = tid & 63;

    for (int c = wave; c < 49; c += 4) {
        float v0 = 0.0f, v1 = 0.0f, v2 = 0.0f, v3 = 0.0f;
        for (int r = lane; r < BLOCKS; r += 256) {
            v0 += partial[c * BLOCKS + r];
            v1 += partial[c * BLOCKS + r + 64];
            v2 += partial[c * BLOCKS + r + 128];
            v3 += partial[c * BLOCKS + r + 192];
        }
        float v = (v0 + v1) + (v2 + v3);
        for (int off = 32; off; off >>= 1) v += __shfl_down(v, off, 64);
        if (lane == 0) cell[c] = v;
    }
    __syncthreads();

    if (tid == 0) {
        float loss = cell[48] / (float)n;   // mean squared diff
        #pragma unroll
        for (int b = 0; b < NBINS; ++b) {
            float cnt = cell[b];
            float s   = cell[16 + b];
            float ss  = cell[32 + b];
            if (cnt > 1.0f)
                loss += (ss - s * s / cnt) / (cnt - 1.0f);  // unbiased var
        }
        out[0] = 0.1f * loss;   // LMBDA
    }
}

extern "C" void kernel_launch(void* const* d_in, const int* in_sizes, int n_in,
                              void* d_out, int out_size, void* d_ws, size_t ws_size,
                              hipStream_t stream)
{
    const float* w     = (const float*)d_in[0];
    const float* wq    = (const float*)d_in[1];
    const int*   nbit  = (const int*)d_in[2];
    const float* alpha = (const float*)d_in[3];
    float* out     = (float*)d_out;
    float* partial = (float*)d_ws;   // fully overwritten each call; no memset needed
    long long n = (long long)in_sizes[0];

    binreg_main<<<BLOCKS, TPB, 0, stream>>>(w, wq, alpha, nbit, partial, n);
    binreg_final<<<1, TPB, 0, stream>>>(partial, out, n);
}